// Round 16
// baseline (227.213 us; speedup 1.0000x reference)
//
#include <hip/hip_runtime.h>
#include <stdint.h>

// Problem constants (B=8, T=2048, D=256, K=8192)
#define M_TOK 16384
#define DIM   256
#define KCB   8192
#define NGRP  8                    // N-groups (blocks in y)
#define GRP   1024                 // codes per group
#define NT    16                   // 64-code tiles per group
#define SHIFT 512.0f               // positivity shift for score packing
#define INV_N (1.0f / 4194304.0f)  // 1/(B*T*D)
#define SC1   0x7F7F7F7F           // E8M0 scale bytes = 2^0 (op_sel-proof)

typedef __attribute__((ext_vector_type(4))) float f32x4;
typedef __attribute__((ext_vector_type(8))) int   i32x8;

// pack 4 floats -> 4 fp8 e4m3 bytes (one dword)
static __device__ __forceinline__ int pk4(float4 f) {
    int o = __builtin_amdgcn_cvt_pk_fp8_f32(f.x, f.y, 0, false);
    o     = __builtin_amdgcn_cvt_pk_fp8_f32(f.z, f.w, o, true);
    return o;
}

// ---------------------------------------------------------------- kernel 1
// Codebook prep: cbt[chunk][code][16B] = fp8 of -c, k-chunk-major;
// chalf = 0.5||c||^2 + SHIFT (exact fp32). Block = 64 codes.
// Block 0 also zeroes the finalize counter (ws re-poisoned every launch).
__global__ void k_prep(const float* __restrict__ cb,
                       unsigned char* __restrict__ cbt,
                       float* __restrict__ chalf,
                       int* __restrict__ cnt) {
    __shared__ float part[4][64];
    const int w  = threadIdx.x >> 6;
    const int l  = threadIdx.x & 63;
    const int c0 = blockIdx.x * 64;
    if (blockIdx.x == 0 && threadIdx.x == 0) cnt[0] = 0;
    const float* row = cb + (size_t)(c0 + l) * DIM;
    float s = 0.0f;
    #pragma unroll
    for (int j = 0; j < 4; j++) {
        int ch = w * 4 + j;
        const float* p = row + ch * 16;
        float4 a = *(const float4*)(p);
        float4 b = *(const float4*)(p + 4);
        float4 c = *(const float4*)(p + 8);
        float4 d = *(const float4*)(p + 12);
        s += a.x*a.x + a.y*a.y + a.z*a.z + a.w*a.w
           + b.x*b.x + b.y*b.y + b.z*b.z + b.w*b.w
           + c.x*c.x + c.y*c.y + c.z*c.z + c.w*c.w
           + d.x*d.x + d.y*d.y + d.z*d.z + d.w*d.w;
        float4 na = {-a.x, -a.y, -a.z, -a.w};
        float4 nb = {-b.x, -b.y, -b.z, -b.w};
        float4 nc = {-c.x, -c.y, -c.z, -c.w};
        float4 nd = {-d.x, -d.y, -d.z, -d.w};
        uint4 r;
        r.x = (unsigned)pk4(na); r.y = (unsigned)pk4(nb);
        r.z = (unsigned)pk4(nc); r.w = (unsigned)pk4(nd);
        *(uint4*)(cbt + ((size_t)ch * KCB + c0 + l) * 16) = r;
    }
    part[w][l] = s;
    __syncthreads();
    if (w == 0) {
        float t = part[0][l] + part[1][l] + part[2][l] + part[3][l];
        chalf[c0 + l] = 0.5f * t + SHIFT;
    }
}

// ----------------------------------------------------------------
// GEMM helpers: explicit two-set register double-buffer (R15 post-mortem:
// without this + a 256-reg budget, the compiler serialized the B loads).
static __device__ __forceinline__ void load_set(
    uint4 (&S)[2][4][2], const unsigned char* bt) {
    #pragma unroll
    for (int ks = 0; ks < 2; ks++)
        #pragma unroll
        for (int ct = 0; ct < 4; ct++)
            #pragma unroll
            for (int h = 0; h < 2; h++)
                S[ks][ct][h] = *(const uint4*)(
                    bt + ((size_t)(ks * 8 + h) * KCB + ct * 16) * 16);
}

static __device__ __forceinline__ void compute_tile(
    const uint4 (&S)[2][4][2], const i32x8 (&afr)[2][2],
    const float* schalf, int t, int lrow, uint32_t (&best)[2][4]) {
    f32x4 acc[2][4];
    #pragma unroll
    for (int ct = 0; ct < 4; ct++) {
        float cs = schalf[t * 64 + ct * 16 + lrow];
        #pragma unroll
        for (int rt = 0; rt < 2; rt++) {
            f32x4 c4 = {cs, cs, cs, cs};
            acc[rt][ct] = c4;
        }
    }
    #pragma unroll
    for (int ks = 0; ks < 2; ks++)
        #pragma unroll
        for (int ct = 0; ct < 4; ct++) {
            union { uint4 q[2]; i32x8 v; } bb;
            bb.q[0] = S[ks][ct][0];
            bb.q[1] = S[ks][ct][1];
            #pragma unroll
            for (int rt = 0; rt < 2; rt++)
                acc[rt][ct] = __builtin_amdgcn_mfma_scale_f32_16x16x128_f8f6f4(
                    afr[rt][ks], bb.v, acc[rt][ct],
                    0, 0, 0, SC1, 0, SC1);   // fmt fp8 e4m3, scales 2^0
        }
    #pragma unroll
    for (int ct = 0; ct < 4; ct++) {
        uint32_t idl = (uint32_t)(t * 64 + ct * 16 + lrow);
        #pragma unroll
        for (int rt = 0; rt < 2; rt++)
            #pragma unroll
            for (int rg = 0; rg < 4; rg++) {
                uint32_t key =
                    (__float_as_uint(acc[rt][ct][rg]) & 0xFFFFFC00u) | idl;
                if (key < best[rt][rg]) best[rt][rg] = key;
            }
    }
}

// ---------------------------------------------------------------- kernel 2
// Barrier-free fp8-MX GEMM+argmin, register-pipelined B. Wave = 32 rows
// (rt=2) x 64 codes (ct=4); grid (128, 8). B fragments load straight from
// global (k-chunk-major; all 4 waves read identical addresses -> L1
// broadcast; co-resident blocks share the group stream in L2). Two 64-reg
// B sets ping-pong with a manually unrolled x2 loop: set for tile t+1 is
// issued a FULL tile-compute (~550 cyc) before use -> counted vmcnt waits,
// no vmcnt(0) barrier drains (impossible to avoid in the LDS structure).
// __launch_bounds__(256,2): 256-reg budget keeps both sets + A resident.
__global__ __launch_bounds__(256, 2) void k_gemm_argmin(
    const float* __restrict__ xs,              // [M_TOK][DIM] fp32
    const unsigned char* __restrict__ cbt,     // [16][KCB][16] fp8 of -c
    const float* __restrict__ chalf,           // [KCB] = 0.5||c||^2+SHIFT
    uint32_t* __restrict__ pkey)               // [M_TOK][NGRP]
{
    __shared__ float schalf[GRP];              // 4 KB (only LDS use)

    const int tid  = threadIdx.x;
    const int w    = tid >> 6;
    const int l    = tid & 63;
    const int lrow = l & 15;
    const int quad = l >> 4;
    const int m0 = blockIdx.x * 128;
    const int g  = blockIdx.y;

    *(float4*)&schalf[tid * 4] = ((const float4*)(chalf + g * GRP))[tid];

    // per-lane B base: chunk = quad*2 (+h, +ks*8), code = lrow (+ct*16, +t*64)
    const unsigned char* bbase =
        cbt + ((size_t)(quad * 2) * KCB + g * GRP + lrow) * 16;

    // ---- A panel: 32 rows x 256 k, fp32 -> fp8 frags (2 rt x 2 ks x 8 dw)
    i32x8 afr[2][2];
    {
        const float* ap = xs + (size_t)(m0 + w * 32 + lrow) * DIM + quad * 32;
        #pragma unroll
        for (int rt = 0; rt < 2; rt++)
            #pragma unroll
            for (int ks = 0; ks < 2; ks++) {
                const float* p = ap + rt * 16 * DIM + ks * 128;
                union { int d[8]; i32x8 v; } aa;
                #pragma unroll
                for (int d = 0; d < 8; d++)
                    aa.d[d] = pk4(*(const float4*)(p + d * 4));
                afr[rt][ks] = aa.v;
            }
    }

    uint32_t best[2][4];
    #pragma unroll
    for (int rt = 0; rt < 2; rt++)
        #pragma unroll
        for (int rg = 0; rg < 4; rg++) best[rt][rg] = 0xFFFFFFFFu;

    __syncthreads();   // schalf ready — the ONLY block-wide barrier

    uint4 b0[2][4][2], b1[2][4][2];
    load_set(b0, bbase);                       // tile 0
    #pragma unroll 1
    for (int tt = 0; tt < 8; tt++) {
        load_set(b1, bbase + (size_t)(2 * tt + 1) * 64 * 16);   // tile 2tt+1
        compute_tile(b0, afr, schalf, 2 * tt, lrow, best);
        if (tt < 7)
            load_set(b0, bbase + (size_t)(2 * tt + 2) * 64 * 16); // tile 2tt+2
        compute_tile(b1, afr, schalf, 2 * tt + 1, lrow, best);
    }

    // min across the 16 lanes of each quad group (same rows, different codes)
    #pragma unroll
    for (int off = 1; off < 16; off <<= 1)
        #pragma unroll
        for (int rt = 0; rt < 2; rt++)
            #pragma unroll
            for (int rg = 0; rg < 4; rg++) {
                uint32_t o = __shfl_xor(best[rt][rg], off);
                if (o < best[rt][rg]) best[rt][rg] = o;
            }
    // wave covers ALL 64 codes of each tile -> writes its 32 rows directly
    if (lrow == 0) {
        #pragma unroll
        for (int rt = 0; rt < 2; rt++)
            #pragma unroll
            for (int rg = 0; rg < 4; rg++)
                pkey[(size_t)(m0 + w * 32 + rt * 16 + quad * 4 + rg) * NGRP + g]
                    = best[rt][rg];
    }
}

// ---------------------------------------------------------------- kernel 3
// Finalize + final write merged (saves one launch). Per row: min over 8
// group keys -> code; exact fp32 ||x-c||^2; block partial; the LAST block
// (atomic counter, R10's verified fence pattern — fences confined to this
// tiny kernel) reduces all 4096 partials and writes the two scalars.
__global__ void k_finalize(const uint32_t* __restrict__ pkey,
                           const float4* __restrict__ xs4,
                           const float4* __restrict__ cb4,
                           float* __restrict__ partial,
                           int* __restrict__ cnt,
                           float* __restrict__ out) {
    __shared__ float sblk[4];
    __shared__ int sLast;
    int w   = threadIdx.x >> 6;
    int row = blockIdx.x * 4 + w;
    int l   = threadIdx.x & 63;
    uint32_t k = 0xFFFFFFFFu;
    int g = 0;
    if (l < 8) { k = pkey[(size_t)row * NGRP + l]; g = l; }
    #pragma unroll
    for (int off = 1; off < 8; off <<= 1) {
        uint32_t ok = __shfl_xor(k, off);
        int      og = __shfl_xor(g, off);
        if (ok < k) { k = ok; g = og; }
    }
    k = __shfl(k, 0);
    g = __shfl(g, 0);
    int code = g * GRP + (int)(k & 1023u);
    float4 x = xs4[(size_t)row * 64 + l];
    float4 c = cb4[(size_t)code * 64 + l];
    float dx = x.x - c.x, dy = x.y - c.y, dz = x.z - c.z, dw = x.w - c.w;
    float s = dx * dx + dy * dy + dz * dz + dw * dw;
    #pragma unroll
    for (int off = 32; off; off >>= 1) s += __shfl_xor(s, off);
    if (l == 0) sblk[w] = s;
    __syncthreads();
    if (threadIdx.x == 0) {
        partial[blockIdx.x] = sblk[0] + sblk[1] + sblk[2] + sblk[3];
        __threadfence();                     // release partial[bx]
        int a = atomicAdd(cnt, 1);
        sLast = (a == 4095);
    }
    __syncthreads();
    if (!sLast) return;

    __threadfence();                         // acquire all partials
    float t = 0.0f;
    for (int i = threadIdx.x; i < 4096; i += 256) t += partial[i];
    #pragma unroll
    for (int off = 32; off; off >>= 1) t += __shfl_xor(t, off);
    if (l == 0) sblk[w] = t;
    __syncthreads();
    if (threadIdx.x == 0) {
        float tot = sblk[0] + sblk[1] + sblk[2] + sblk[3];
        float commit = tot * INV_N;
        out[0] = 0.25f * commit;   // loss
        out[1] = commit;           // commit_loss
    }
}

extern "C" void kernel_launch(void* const* d_in, const int* in_sizes, int n_in,
                              void* d_out, int out_size, void* d_ws, size_t ws_size,
                              hipStream_t stream) {
    const float* xs = (const float*)d_in[0];
    // d_in[1] = ilens (int64, all == T) -> slice is a no-op, unused
    const float* cb = (const float*)d_in[2];

    char* ws = (char*)d_ws;
    unsigned char* cbt     = (unsigned char*)(ws + 256);            // 2 MiB
    float*         chalf   = (float*)(ws + 256 + 2097152);          // 32 KiB
    uint32_t*      pkey    = (uint32_t*)(ws + 256 + 2129920);       // 512 KiB
    float*         partial = (float*)(ws + 256 + 2654208);          // 16 KiB
    int*           cnt     = (int*)  (ws + 256 + 2670592);          // 4 B

    k_prep<<<128, 256, 0, stream>>>(cb, cbt, chalf, cnt);
    dim3 g(M_TOK / 128, NGRP);
    k_gemm_argmin<<<g, 256, 0, stream>>>(xs, cbt, chalf, pkey);
    k_finalize<<<4096, 256, 0, stream>>>(pkey, (const float4*)xs,
                                         (const float4*)cb, partial, cnt,
                                         (float*)d_out);
}

// Round 17
// 119.625 us; speedup vs baseline: 1.8994x; 1.8994x over previous
//
#include <hip/hip_runtime.h>
#include <stdint.h>

// Problem constants (B=8, T=2048, D=256, K=8192)
#define M_TOK 16384
#define DIM   256
#define KCB   8192
#define NGRP  8                    // N-groups (blocks in y)
#define GRP   1024                 // codes per group
#define NCHK  16                   // 16B fp8 k-chunks per row (256*1B/16B)
#define NT    16                   // 64-code tiles per group
#define SHIFT 512.0f               // positivity shift for score packing
#define INV_N (1.0f / 4194304.0f)  // 1/(B*T*D)
#define SC1   0x7F7F7F7F           // E8M0 scale bytes = 2^0 (op_sel-proof)

typedef __attribute__((ext_vector_type(4))) float f32x4;
typedef __attribute__((ext_vector_type(8))) int   i32x8;

// Async global->LDS DMA, 16 B/lane; LDS dest = wave-uniform base + lane*16.
static __device__ __forceinline__ void lds_cp16(const void* g, void* l) {
    __builtin_amdgcn_global_load_lds(
        (const __attribute__((address_space(1))) void*)g,
        (__attribute__((address_space(3))) void*)l, 16, 0, 0);
}

// pack 4 floats -> 4 fp8 e4m3 bytes (one dword)
static __device__ __forceinline__ int pk4(float4 f) {
    int o = __builtin_amdgcn_cvt_pk_fp8_f32(f.x, f.y, 0, false);
    o     = __builtin_amdgcn_cvt_pk_fp8_f32(f.z, f.w, o, true);
    return o;
}

// ---------------------------------------------------------------- kernel 1
// Codebook prep: cbt[chunk][code][16B] = fp8 of -c, k-chunk-major (GEMM LDS
// staging reads 1KB-contiguous); chalf = 0.5||c||^2 + SHIFT (exact fp32).
// Block = 64 codes; wave w handles k-chunks [4w, 4w+4); lane = code.
__global__ void k_prep(const float* __restrict__ cb,
                       unsigned char* __restrict__ cbt,
                       float* __restrict__ chalf) {
    __shared__ float part[4][64];
    const int w  = threadIdx.x >> 6;
    const int l  = threadIdx.x & 63;
    const int c0 = blockIdx.x * 64;
    const float* row = cb + (size_t)(c0 + l) * DIM;
    float s = 0.0f;
    #pragma unroll
    for (int j = 0; j < 4; j++) {
        int ch = w * 4 + j;
        const float* p = row + ch * 16;
        float4 a = *(const float4*)(p);
        float4 b = *(const float4*)(p + 4);
        float4 c = *(const float4*)(p + 8);
        float4 d = *(const float4*)(p + 12);
        s += a.x*a.x + a.y*a.y + a.z*a.z + a.w*a.w
           + b.x*b.x + b.y*b.y + b.z*b.z + b.w*b.w
           + c.x*c.x + c.y*c.y + c.z*c.z + c.w*c.w
           + d.x*d.x + d.y*d.y + d.z*d.z + d.w*d.w;
        float4 na = {-a.x, -a.y, -a.z, -a.w};
        float4 nb = {-b.x, -b.y, -b.z, -b.w};
        float4 nc = {-c.x, -c.y, -c.z, -c.w};
        float4 nd = {-d.x, -d.y, -d.z, -d.w};
        uint4 r;
        r.x = (unsigned)pk4(na); r.y = (unsigned)pk4(nb);
        r.z = (unsigned)pk4(nc); r.w = (unsigned)pk4(nd);
        *(uint4*)(cbt + ((size_t)ch * KCB + c0 + l) * 16) = r;
    }
    part[w][l] = s;
    __syncthreads();
    if (w == 0) {
        float t = part[0][l] + part[1][l] + part[2][l] + part[3][l];
        chalf[c0 + l] = 0.5f * t + SHIFT;
    }
}

// ---------------------------------------------------------------- kernel 2
// fp8-MX double-buffered GEMM+argmin — the session optimum (R12: 48.4 us).
// 128-row blocks, grid (128, 8) = 1024 blocks = 4 blocks/CU. Wave = 32 rows
// (rt=2) x 64 codes (ct=4), ksteps=2 (K=128/MFMA). One barrier per tile
// drains the DMA issued one full compute phase earlier. LDS 36 KB, VGPR 64
// (safe under the (256,4) 128-reg cap — R13's 64-row variant spilled).
// acc init = 0.5||c||^2+SHIFT (fp32 exact), B = -c => acc = positive score;
// argmin kept as packed u32 key = (score_bits & ~1023) | group-local id.
__global__ __launch_bounds__(256, 4) void k_gemm_argmin(
    const float* __restrict__ xs,              // [M_TOK][DIM] fp32
    const unsigned char* __restrict__ cbt,     // [NCHK][KCB][16] fp8 of -c
    const float* __restrict__ chalf,           // [KCB] = 0.5||c||^2+SHIFT
    uint32_t* __restrict__ pkey)               // [M_TOK][NGRP]
{
    __shared__ __align__(16) unsigned char Bs[2][NCHK][64][16];   // 32 KB
    __shared__ float schalf[GRP];                                  // 4 KB

    const int tid  = threadIdx.x;
    const int w    = tid >> 6;
    const int l    = tid & 63;
    const int lrow = l & 15;
    const int quad = l >> 4;
    const int m0 = blockIdx.x * 128;
    const int g  = blockIdx.y;

    *(float4*)&schalf[tid * 4] = ((const float4*)(chalf + g * GRP))[tid];

    // staging: wave w supplies chunks [4w,4w+4); lane = code in tile
    const unsigned char* bsrc = cbt + ((size_t)(w * 4) * KCB + g * GRP + l) * 16;

    #pragma unroll
    for (int j = 0; j < 4; j++)
        lds_cp16(bsrc + (size_t)j * KCB * 16, &Bs[0][w * 4 + j][0][0]);

    // ---- A panel: 32 rows x 256 k, fp32 -> fp8 frags (2 rt x 2 ks x 8 dw)
    i32x8 afr[2][2];
    {
        const float* ap = xs + (size_t)(m0 + w * 32 + lrow) * DIM + quad * 32;
        #pragma unroll
        for (int rt = 0; rt < 2; rt++)
            #pragma unroll
            for (int ks = 0; ks < 2; ks++) {
                const float* p = ap + rt * 16 * DIM + ks * 128;
                union { int d[8]; i32x8 v; } aa;
                #pragma unroll
                for (int d = 0; d < 8; d++)
                    aa.d[d] = pk4(*(const float4*)(p + d * 4));
                afr[rt][ks] = aa.v;
            }
    }

    uint32_t best[2][4];
    #pragma unroll
    for (int rt = 0; rt < 2; rt++)
        #pragma unroll
        for (int rg = 0; rg < 4; rg++) best[rt][rg] = 0xFFFFFFFFu;

    #pragma unroll 1
    for (int t = 0; t < NT; t++) {
        const int cur = t & 1;
        __syncthreads();   // drains DMA(t) issued one compute phase ago
        if (t < NT - 1) {  // prefetch t+1 AFTER the barrier
            #pragma unroll
            for (int j = 0; j < 4; j++)
                lds_cp16(bsrc + ((size_t)j * KCB + (t + 1) * 64) * 16,
                         &Bs[1 - cur][w * 4 + j][0][0]);
        }

        f32x4 acc[2][4];
        #pragma unroll
        for (int ct = 0; ct < 4; ct++) {
            float cs = schalf[t * 64 + ct * 16 + lrow];
            #pragma unroll
            for (int rt = 0; rt < 2; rt++) {
                f32x4 c4 = {cs, cs, cs, cs};
                acc[rt][ct] = c4;
            }
        }
        #pragma unroll
        for (int ks = 0; ks < 2; ks++) {
            const int ch = ks * 8 + quad * 2;   // lane's k-window = 2 chunks
            i32x8 bfr[4];
            #pragma unroll
            for (int ct = 0; ct < 4; ct++) {
                union { uint4 q[2]; i32x8 v; } bb;
                bb.q[0] = *(const uint4*)&Bs[cur][ch][ct * 16 + lrow][0];
                bb.q[1] = *(const uint4*)&Bs[cur][ch + 1][ct * 16 + lrow][0];
                bfr[ct] = bb.v;
            }
            #pragma unroll
            for (int rt = 0; rt < 2; rt++)
                #pragma unroll
                for (int ct = 0; ct < 4; ct++)
                    acc[rt][ct] = __builtin_amdgcn_mfma_scale_f32_16x16x128_f8f6f4(
                        afr[rt][ks], bfr[ct], acc[rt][ct],
                        0, 0,              // cbsz, blgp: fmt 0 = fp8 e4m3
                        0, SC1,            // op_sel_a, scale_a = 2^0
                        0, SC1);           // op_sel_b, scale_b = 2^0
        }
        // fold scores into packed keys: (score_bits & ~1023) | group-local id
        #pragma unroll
        for (int ct = 0; ct < 4; ct++) {
            uint32_t idl = (uint32_t)(t * 64 + ct * 16 + lrow);
            #pragma unroll
            for (int rt = 0; rt < 2; rt++)
                #pragma unroll
                for (int rg = 0; rg < 4; rg++) {
                    uint32_t key =
                        (__float_as_uint(acc[rt][ct][rg]) & 0xFFFFFC00u) | idl;
                    if (key < best[rt][rg]) best[rt][rg] = key;
                }
        }
    }

    // min across the 16 lanes of each quad group (same rows, different codes)
    #pragma unroll
    for (int off = 1; off < 16; off <<= 1)
        #pragma unroll
        for (int rt = 0; rt < 2; rt++)
            #pragma unroll
            for (int rg = 0; rg < 4; rg++) {
                uint32_t o = __shfl_xor(best[rt][rg], off);
                if (o < best[rt][rg]) best[rt][rg] = o;
            }
    if (lrow == 0) {
        #pragma unroll
        for (int rt = 0; rt < 2; rt++)
            #pragma unroll
            for (int rg = 0; rg < 4; rg++)
                pkey[(size_t)(m0 + w * 32 + rt * 16 + quad * 4 + rg) * NGRP + g]
                    = best[rt][rg];
    }
}

// ---------------------------------------------------------------- kernel 3
// Per row: min over 8 group keys -> final code; exact fp32 ||x-c||^2;
// per-block LDS reduce -> partial[blockIdx]. NO global atomics/fences
// (R1: 16k same-addr atomics = 211 us; R16: 4k atomics+fences = 105 us).
__global__ void k_finalize(const uint32_t* __restrict__ pkey,
                           const float4* __restrict__ xs4,
                           const float4* __restrict__ cb4,
                           float* __restrict__ partial) {
    __shared__ float sblk[4];
    int w   = threadIdx.x >> 6;
    int row = blockIdx.x * 4 + w;
    int l   = threadIdx.x & 63;
    uint32_t k = 0xFFFFFFFFu;
    int g = 0;
    if (l < 8) { k = pkey[(size_t)row * NGRP + l]; g = l; }
    #pragma unroll
    for (int off = 1; off < 8; off <<= 1) {
        uint32_t ok = __shfl_xor(k, off);
        int      og = __shfl_xor(g, off);
        if (ok < k) { k = ok; g = og; }
    }
    k = __shfl(k, 0);
    g = __shfl(g, 0);
    int code = g * GRP + (int)(k & 1023u);
    float4 x = xs4[(size_t)row * 64 + l];
    float4 c = cb4[(size_t)code * 64 + l];
    float dx = x.x - c.x, dy = x.y - c.y, dz = x.z - c.z, dw = x.w - c.w;
    float s = dx * dx + dy * dy + dz * dz + dw * dw;
    #pragma unroll
    for (int off = 32; off; off >>= 1) s += __shfl_xor(s, off);
    if (l == 0) sblk[w] = s;
    __syncthreads();
    if (threadIdx.x == 0)
        partial[blockIdx.x] = sblk[0] + sblk[1] + sblk[2] + sblk[3];
}

// ---------------------------------------------------------------- kernel 4
__global__ void k_write(const float* __restrict__ partial,
                        float* __restrict__ out) {
    __shared__ float swv[16];
    int tid = threadIdx.x;                    // 1024 threads = 16 waves
    float s = partial[tid] + partial[tid + 1024] +
              partial[tid + 2048] + partial[tid + 3072];
    #pragma unroll
    for (int off = 32; off; off >>= 1) s += __shfl_xor(s, off);
    if ((tid & 63) == 0) swv[tid >> 6] = s;
    __syncthreads();
    if (tid == 0) {
        float t = 0.0f;
        #pragma unroll
        for (int i = 0; i < 16; i++) t += swv[i];
        float commit = t * INV_N;
        out[0] = 0.25f * commit;   // loss
        out[1] = commit;           // commit_loss
    }
}

extern "C" void kernel_launch(void* const* d_in, const int* in_sizes, int n_in,
                              void* d_out, int out_size, void* d_ws, size_t ws_size,
                              hipStream_t stream) {
    const float* xs = (const float*)d_in[0];
    // d_in[1] = ilens (int64, all == T) -> slice is a no-op, unused
    const float* cb = (const float*)d_in[2];

    char* ws = (char*)d_ws;
    unsigned char* cbt     = (unsigned char*)(ws + 256);            // 2 MiB
    float*         chalf   = (float*)(ws + 256 + 2097152);          // 32 KiB
    uint32_t*      pkey    = (uint32_t*)(ws + 256 + 2129920);       // 512 KiB
    float*         partial = (float*)(ws + 256 + 2654208);          // 16 KiB

    k_prep<<<128, 256, 0, stream>>>(cb, cbt, chalf);
    dim3 g(M_TOK / 128, NGRP);
    k_gemm_argmin<<<g, 256, 0, stream>>>(xs, cbt, chalf, pkey);
    k_finalize<<<4096, 256, 0, stream>>>(pkey, (const float4*)xs,
                                         (const float4*)cb, partial);
    k_write<<<1, 1024, 0, stream>>>(partial, (float*)d_out);
}